// Round 5
// baseline (319.905 us; speedup 1.0000x reference)
//
#include <hip/hip_runtime.h>

#define BB 16
#define TT 144
#define TP1 145
#define HW8 2048   // f8 groups per image
#define LL 6
#define BIGE 1e30
#define NB_STEP (BB * TP1)   // 2320
#define CHUNK 290            // 2320 / 8 XCDs

typedef float f8 __attribute__((ext_vector_type(8)));

// ---- workspace layout (bytes) ----
static const size_t OFF_A0    = 0;                  // state ping-pong: B*HW f32 each
static const size_t OFF_M0    = 1u << 20;
static const size_t OFF_A1    = 2u << 20;
static const size_t OFF_M1    = 3u << 20;
static const size_t OFF_ERRA  = 4u << 20;           // B*145 f64 score ping-pong
static const size_t OFF_ERRB  = (4u << 20) + 32768;
static const size_t OFF_BELOW = 5u << 20;           // B*T*HW f32 = 150,994,944
static const size_t WS_FULL   = OFF_BELOW + 150994944ull;

__device__ __forceinline__ float hsum8(f8 v) {
    return (((v.s0 + v.s1) + (v.s2 + v.s3)) + ((v.s4 + v.s5) + (v.s6 + v.s7)));
}

__device__ __forceinline__ double blk_reduce(double s) {
    for (int off = 32; off; off >>= 1) s += __shfl_down(s, off);
    __shared__ double smr[4];
    if ((threadIdx.x & 63) == 0) smr[threadIdx.x >> 6] = s;
    __syncthreads();
    return smr[0] + smr[1] + smr[2] + smr[3];
}

// Deterministic argmin over err_b[0..144]; ties -> lowest t (matches jnp.argmin).
__device__ __forceinline__ int blk_argmin(const double* __restrict__ err_b) {
    const int tid = threadIdx.x;
    double e = 1e301; int idx = TP1;
    if (tid < TP1) { e = err_b[tid]; idx = tid; }
    for (int off = 32; off; off >>= 1) {
        double oe = __shfl_down(e, off);
        int    oi = __shfl_down(idx, off);
        if (oe < e || (oe == e && oi < idx)) { e = oe; idx = oi; }
    }
    __shared__ double se[4]; __shared__ int si[4]; __shared__ int ssel;
    if ((tid & 63) == 0) { se[tid >> 6] = e; si[tid >> 6] = idx; }
    __syncthreads();
    if (tid == 0) {
        double be = se[0]; int bi = si[0];
        for (int w = 1; w < 4; ++w)
            if (se[w] < be || (se[w] == be && si[w] < bi)) { be = se[w]; bi = si[w]; }
        ssel = bi;
    }
    __syncthreads();
    return ssel;
}

// Build below = t*m + bg*(1-m) (f32) and step-0 scores (A=0, M=1 -> u=x, v=1).
// temps/masks are read exactly once across the whole op -> non-temporal.
template <bool STORE>
__global__ void k_build(const f8* __restrict__ temps, const f8* __restrict__ masks,
                        const f8* __restrict__ bg, const f8* __restrict__ x,
                        f8* __restrict__ below, double* __restrict__ err) {
    const int t = blockIdx.x, b = blockIdx.y, tid = threadIdx.x;
    const f8* xb = x + (size_t)b * HW8;
    double s = 0.0;
    if (t == 0) {
        // w = 5: per-element term = 25 - 10x
        for (int j = tid; j < HW8; j += 256)
            s += (double)(200.f - 10.f * hsum8(xb[j]));
    } else {
        const size_t row = ((size_t)(b * TT + t - 1)) * HW8;
        for (int j = tid; j < HW8; j += 256) {
            f8 tv = __builtin_nontemporal_load(&temps[row + j]);
            f8 mv = __builtin_nontemporal_load(&masks[row + j]);
            f8 bv = bg[j], xv = xb[j];
            f8 w = tv * mv + bv * (1.f - mv);
            if (STORE) below[row + j] = w;
            s += (double)hsum8(w * (w - 2.f * xv));
        }
    }
    double tot = blk_reduce(s);
    if (tid == 0) err[b * TP1 + t] = tot;
}

// One greedy step, fully fused:
//   sel = argmin(err_old) ; state_new = update(state_old, sel) computed in registers;
//   score(t) = sum( v*w^2 - 2*u*w ) with u,v derived on the fly; t==0 block persists
//   state_new + objects/masks/ids for this selection.
// MODE 0: w from precomputed below; MODE 1: recompute from temps/masks/bg.
template <bool FIRST, int MODE>
__global__ void k_step(const f8* __restrict__ temps, const f8* __restrict__ masks,
                       const f8* __restrict__ bg, const f8* __restrict__ x,
                       const f8* __restrict__ below,
                       const double* __restrict__ err_old, double* __restrict__ err_new,
                       const f8* __restrict__ Aold, const f8* __restrict__ Mold,
                       f8* __restrict__ Anew, f8* __restrict__ Mnew,
                       f8* __restrict__ out_obj, f8* __restrict__ out_msk,
                       float* __restrict__ out_ids, int slot) {
    // XCD-chunked bijective swizzle: 2320 = 8*290 -> each XCD owns 2 whole batches.
    const int lin = blockIdx.x;
    const int wg  = (lin & 7) * CHUNK + (lin >> 3);
    const int b   = wg / TP1;
    const int t   = wg - b * TP1;
    const int tid = threadIdx.x;

    const int sel = blk_argmin(err_old + b * TP1);

    const double my_old = err_old[b * TP1 + t];
    const bool masked = (t != 0) && (t == sel || my_old >= 0.5 * BIGE);
    if (masked) {
        if (tid == 0) err_new[b * TP1 + t] = BIGE;
        return;
    }

    const bool selzero = (sel == 0);
    const size_t selrow = selzero ? 0 : ((size_t)(b * TT + sel - 1)) * HW8;
    const size_t rowt   = (t > 0) ? ((size_t)(b * TT + t - 1)) * HW8 : 0;
    const f8* xb = x + (size_t)b * HW8;
    const f8* Ab = Aold + (size_t)b * HW8;
    const f8* Mb = Mold + (size_t)b * HW8;
    const size_t ob = ((size_t)(b * LL + slot)) * HW8;
    const bool writer = (t == 0);

    double s = 0.0;
    for (int j = tid; j < HW8; j += 256) {
        f8 st, sm;
        if (selzero) { st = (f8)(5.f); sm = (f8)(1.f); }
        else         { st = temps[selrow + j]; sm = masks[selrow + j]; }
        f8 a, mp;
        if (FIRST) { a = (f8)(0.f); mp = (f8)(1.f); }
        else       { a = Ab[j]; mp = Mb[j]; }
        a = a + mp * st * sm;           // same expression/order as the passing R3 path
        mp = mp * (1.f - sm);
        if (writer) {
            Anew[(size_t)b * HW8 + j] = a;
            Mnew[(size_t)b * HW8 + j] = mp;
            out_obj[ob + j] = st;
            out_msk[ob + j] = sm;
        }
        f8 xv = xb[j];
        f8 u = (xv - a) * mp;
        f8 v = mp * mp;
        if (t == 0) {
            s += (double)hsum8(25.f * v - 10.f * u);
        } else {
            f8 w;
            if (MODE == 0) w = below[rowt + j];
            else {
                f8 tv = temps[rowt + j], mv = masks[rowt + j];
                w = tv * mv + bg[j] * (1.f - mv);
            }
            s += (double)hsum8(w * (v * w - 2.f * u));
        }
    }
    double tot = blk_reduce(s);
    if (tid == 0) {
        err_new[b * TP1 + t] = tot;
        if (writer) out_ids[b * LL + slot] = (float)sel;
    }
}

// Final: sel_5 = argmin, apply update, emit obj/msk/ids slot 5 and recons = A + M*bg.
__global__ void k_final(const f8* __restrict__ temps, const f8* __restrict__ masks,
                        const f8* __restrict__ bg,
                        const double* __restrict__ err_old,
                        const f8* __restrict__ Aold, const f8* __restrict__ Mold,
                        f8* __restrict__ out_rec, f8* __restrict__ out_obj,
                        f8* __restrict__ out_msk, float* __restrict__ out_ids) {
    const int tid = threadIdx.x;
    const int gid = blockIdx.x * 256 + tid;      // 32768 f8 groups, 128 blocks
    const int b = gid >> 11;                     // uniform per block (8 blocks/batch)
    const int j = gid & (HW8 - 1);

    const int sel = blk_argmin(err_old + b * TP1);

    f8 st, sm;
    if (sel == 0) { st = (f8)(5.f); sm = (f8)(1.f); }
    else {
        size_t base = ((size_t)(b * TT + sel - 1)) * HW8 + j;
        st = temps[base]; sm = masks[base];
    }
    f8 a = Aold[(size_t)b * HW8 + j], mp = Mold[(size_t)b * HW8 + j];
    a = a + mp * st * sm;
    mp = mp * (1.f - sm);
    const size_t ob = ((size_t)(b * LL + (LL - 1))) * HW8 + j;
    out_obj[ob] = st;
    out_msk[ob] = sm;
    out_rec[(size_t)b * HW8 + j] = a + mp * bg[j];
    if (tid == 0 && (blockIdx.x & 7) == 0)
        out_ids[b * LL + (LL - 1)] = (float)sel;
}

extern "C" void kernel_launch(void* const* d_in, const int* in_sizes, int n_in,
                              void* d_out, int out_size, void* d_ws, size_t ws_size,
                              hipStream_t stream) {
    const f8* x     = (const f8*)d_in[0];
    const f8* temps = (const f8*)d_in[1];
    const f8* masks = (const f8*)d_in[2];
    const f8* bg    = (const f8*)d_in[3];

    float* out      = (float*)d_out;
    f8*    out_rec  = (f8*)out;                           // B*HW
    f8*    out_obj  = (f8*)(out + 262144);                // B*L*HW
    f8*    out_msk  = (f8*)(out + 262144 + 1572864);      // B*L*HW
    float* out_ids  = out + 262144 + 2 * 1572864;         // B*L

    char* ws = (char*)d_ws;
    f8*     A0    = (f8*)(ws + OFF_A0);
    f8*     M0    = (f8*)(ws + OFF_M0);
    f8*     A1    = (f8*)(ws + OFF_A1);
    f8*     M1    = (f8*)(ws + OFF_M1);
    double* errA  = (double*)(ws + OFF_ERRA);
    double* errB  = (double*)(ws + OFF_ERRB);
    f8*     below = (f8*)(ws + OFF_BELOW);

    const bool full = (ws_size >= WS_FULL);

    if (full) {
        k_build<true><<<dim3(TP1, BB), 256, 0, stream>>>(temps, masks, bg, x, below, errA);
        // i=1: errA->errB, state -> buf0 (FIRST)
        k_step<true, 0><<<NB_STEP, 256, 0, stream>>>(temps, masks, bg, x, below,
            errA, errB, nullptr, nullptr, A0, M0, out_obj, out_msk, out_ids, 0);
        // i=2: errB->errA, buf0->buf1
        k_step<false, 0><<<NB_STEP, 256, 0, stream>>>(temps, masks, bg, x, below,
            errB, errA, A0, M0, A1, M1, out_obj, out_msk, out_ids, 1);
        // i=3: errA->errB, buf1->buf0
        k_step<false, 0><<<NB_STEP, 256, 0, stream>>>(temps, masks, bg, x, below,
            errA, errB, A1, M1, A0, M0, out_obj, out_msk, out_ids, 2);
        // i=4: errB->errA, buf0->buf1
        k_step<false, 0><<<NB_STEP, 256, 0, stream>>>(temps, masks, bg, x, below,
            errB, errA, A0, M0, A1, M1, out_obj, out_msk, out_ids, 3);
        // i=5: errA->errB, buf1->buf0
        k_step<false, 0><<<NB_STEP, 256, 0, stream>>>(temps, masks, bg, x, below,
            errA, errB, A1, M1, A0, M0, out_obj, out_msk, out_ids, 4);
        // final: errB, state buf0
        k_final<<<128, 256, 0, stream>>>(temps, masks, bg, errB, A0, M0,
            out_rec, out_obj, out_msk, out_ids);
    } else {
        k_build<false><<<dim3(TP1, BB), 256, 0, stream>>>(temps, masks, bg, x, nullptr, errA);
        k_step<true, 1><<<NB_STEP, 256, 0, stream>>>(temps, masks, bg, x, nullptr,
            errA, errB, nullptr, nullptr, A0, M0, out_obj, out_msk, out_ids, 0);
        k_step<false, 1><<<NB_STEP, 256, 0, stream>>>(temps, masks, bg, x, nullptr,
            errB, errA, A0, M0, A1, M1, out_obj, out_msk, out_ids, 1);
        k_step<false, 1><<<NB_STEP, 256, 0, stream>>>(temps, masks, bg, x, nullptr,
            errA, errB, A1, M1, A0, M0, out_obj, out_msk, out_ids, 2);
        k_step<false, 1><<<NB_STEP, 256, 0, stream>>>(temps, masks, bg, x, nullptr,
            errB, errA, A0, M0, A1, M1, out_obj, out_msk, out_ids, 3);
        k_step<false, 1><<<NB_STEP, 256, 0, stream>>>(temps, masks, bg, x, nullptr,
            errA, errB, A1, M1, A0, M0, out_obj, out_msk, out_ids, 4);
        k_final<<<128, 256, 0, stream>>>(temps, masks, bg, errB, A0, M0,
            out_rec, out_obj, out_msk, out_ids);
    }
}

// Round 6
// 257.282 us; speedup vs baseline: 1.2434x; 1.2434x over previous
//
#include <hip/hip_runtime.h>
#include <math.h>

#define BB 16
#define TT 144
#define TP1 145
#define HW4 4096   // f4 groups per image
#define HW8 2048   // f8/u16x8 groups per image
#define LL 6
#define BIGE 1e30
#define NB_STEP (BB * TP1)   // 2320
#define CHUNK 290            // 2320 / 8 XCDs (bijective)
#define EPSQ 7.62951e-6      // 0.5/65535: u16 quantization abs error bound on w in [0,1]

typedef float          f4    __attribute__((ext_vector_type(4)));
typedef float          f8    __attribute__((ext_vector_type(8)));
typedef unsigned short u16x4 __attribute__((ext_vector_type(4)));
typedef unsigned short u16x8 __attribute__((ext_vector_type(8)));

// ---- workspace layout (bytes) ----
static const size_t OFF_A     = 0;                   // B*HW f32 (1 MB each)
static const size_t OFF_M     = 1u << 20;
static const size_t OFF_U     = 2u << 20;
static const size_t OFF_V     = 3u << 20;
static const size_t OFF_ERR32 = 4u << 20;            // B*145 f64
static const size_t OFF_ERR16 = (4u << 20) + 32768;  // B*145 f64 (screen scores)
static const size_t OFF_D     = (4u << 20) + 65536;  // B f64 (bound accumulator)
static const size_t OFF_USED  = (4u << 20) + 81920;  // B*145 i32
static const size_t OFF_WQ    = (4u << 20) + 131072; // B*T*HW u16 = 75,497,472
static const size_t WS_FULL   = OFF_WQ + 75497472ull;

__device__ __forceinline__ float hsum(f4 v) { return ((v.x + v.y) + v.z) + v.w; }
__device__ __forceinline__ float hsum8(f8 v) {
    return (((v.s0 + v.s1) + (v.s2 + v.s3)) + ((v.s4 + v.s5) + (v.s6 + v.s7)));
}

__device__ __forceinline__ double blk_reduce(double s) {
    for (int off = 32; off; off >>= 1) s += __shfl_down(s, off);
    __shared__ double smr[4];
    if ((threadIdx.x & 63) == 0) smr[threadIdx.x >> 6] = s;
    __syncthreads();
    return smr[0] + smr[1] + smr[2] + smr[3];
}

__device__ __forceinline__ void blk_reduce2(double& a, double& b) {
    for (int off = 32; off; off >>= 1) { a += __shfl_down(a, off); b += __shfl_down(b, off); }
    __shared__ double sa[4], sb[4];
    if ((threadIdx.x & 63) == 0) { sa[threadIdx.x >> 6] = a; sb[threadIdx.x >> 6] = b; }
    __syncthreads();
    a = sa[0] + sa[1] + sa[2] + sa[3];
    b = sb[0] + sb[1] + sb[2] + sb[3];
}

// Build wq = u16(round(65535*w)), w = t*m + bg*(1-m) in f32; EXACT step-0 scores
// (A=0,M=1 -> u=x,v=1) from the in-register f32 w; zero used[].
// temps/masks read exactly once across the whole op -> non-temporal.
__global__ void k_build(const f4* __restrict__ temps, const f4* __restrict__ masks,
                        const f4* __restrict__ bg, const f4* __restrict__ x,
                        u16x4* __restrict__ wq, double* __restrict__ err32,
                        int* __restrict__ used) {
    const int t = blockIdx.x, b = blockIdx.y, tid = threadIdx.x;
    const f4* xb = x + (size_t)b * HW4;
    double s = 0.0;
    if (t == 0) {
        if (tid < TP1) used[b * TP1 + tid] = 0;
        for (int j = tid; j < HW4; j += 256)
            s += (double)(100.f - 10.f * hsum(xb[j]));
    } else {
        const size_t row = ((size_t)(b * TT + t - 1)) * HW4;
        for (int j = tid; j < HW4; j += 256) {
            f4 tv = __builtin_nontemporal_load(&temps[row + j]);
            f4 mv = __builtin_nontemporal_load(&masks[row + j]);
            f4 bv = bg[j], xv = xb[j];
            f4 w = tv * mv + bv * (1.f - mv);
            wq[row + j] = __builtin_convertvector(w * 65535.f + 0.5f, u16x4);
            s += (double)hsum(w * (w - 2.f * xv));
        }
    }
    double tot = blk_reduce(s);
    if (tid == 0) err32[b * TP1 + t] = tot;
}

// Screen pass: err16[b][t] = sum(v*wq^2 - 2*u*wq); t==0 exact + D_b = sum(v+|u|).
__global__ void k_err16(const u16x8* __restrict__ wq,
                        const f4* __restrict__ u4, const f4* __restrict__ v4,
                        const int* __restrict__ used,
                        double* __restrict__ err16, double* __restrict__ D) {
    // XCD-chunked bijective swizzle (2320 = 8*290): u,v,x of a batch stay in-XCD L2.
    const int lin = blockIdx.x;
    const int wg  = (lin & 7) * CHUNK + (lin >> 3);
    const int b   = wg / TP1;
    const int t   = wg - b * TP1;
    const int tid = threadIdx.x;
    if (t != 0 && used[b * TP1 + t]) {
        if (tid == 0) err16[b * TP1 + t] = BIGE;
        return;
    }
    if (t == 0) {
        const f4* ub = u4 + (size_t)b * HW4;
        const f4* vb = v4 + (size_t)b * HW4;
        double s = 0.0, d = 0.0;
        for (int j = tid; j < HW4; j += 256) {
            f4 uu = ub[j], vv = vb[j];
            s += (double)(25.f * hsum(vv) - 10.f * hsum(uu));
            f4 au = {fabsf(uu.x), fabsf(uu.y), fabsf(uu.z), fabsf(uu.w)};
            d += (double)hsum(vv + au);
        }
        blk_reduce2(s, d);
        if (tid == 0) { err16[b * TP1] = s; D[b] = d; }
        return;
    }
    const f8* ub = (const f8*)(u4 + (size_t)b * HW4);
    const f8* vb = (const f8*)(v4 + (size_t)b * HW4);
    const u16x8* wb = wq + ((size_t)(b * TT + t - 1)) * HW8;
    double s = 0.0;
    for (int j = tid; j < HW8; j += 256) {
        f8 w = __builtin_convertvector(wb[j], f8) * (1.f / 65535.f);
        f8 uu = ub[j], vv = vb[j];
        s += (double)hsum8(w * (vv * w - 2.f * uu));
    }
    double tot = blk_reduce(s);
    if (tid == 0) err16[b * TP1 + t] = tot;
}

// Sound refine. |s16 - s32| <= 2*EPSQ*D_b (+eps), so shortlist = {t: s16 <= min16 + margin},
// margin = 4*EPSQ*D_b + 0.05. If the shortlist is a singleton it IS the true argmin ->
// no re-eval. Otherwise shortlist members get the exact f32 eval (verbatim R3 arithmetic).
__global__ void k_refine(const f4* __restrict__ temps, const f4* __restrict__ masks,
                         const f4* __restrict__ bg,
                         const f4* __restrict__ u4, const f4* __restrict__ v4,
                         const double* __restrict__ err16, const double* __restrict__ D,
                         double* __restrict__ err32) {
    const int t = blockIdx.x, b = blockIdx.y, tid = threadIdx.x;
    double e = (tid < TP1) ? err16[b * TP1 + tid] : 1e300;
    double m = e;
    for (int off = 32; off; off >>= 1) {
        double o = __shfl_down(m, off);
        m = (o < m) ? o : m;
    }
    __shared__ double sm[4]; __shared__ double smin_s; __shared__ int scnt[4];
    if ((tid & 63) == 0) sm[tid >> 6] = m;
    __syncthreads();
    if (tid == 0) {
        double a = (sm[0] < sm[1]) ? sm[0] : sm[1];
        double c = (sm[2] < sm[3]) ? sm[2] : sm[3];
        smin_s = (a < c) ? a : c;
    }
    __syncthreads();
    const double thr = smin_s + (4.0 * EPSQ * D[b] + 0.05);
    int flag = (tid < TP1) && (e <= thr);
    unsigned long long bal = __ballot(flag);
    if ((tid & 63) == 0) scnt[tid >> 6] = __popcll(bal);
    __syncthreads();
    const int cnt = scnt[0] + scnt[1] + scnt[2] + scnt[3];
    const double mys = err16[b * TP1 + t];
    if (mys > thr) { if (tid == 0) err32[b * TP1 + t] = BIGE; return; }
    if (cnt == 1 || t == 0) {  // singleton -> provably the argmin; t0 s16 is already exact
        if (tid == 0) err32[b * TP1 + t] = mys;
        return;
    }
    const f4* ub = u4 + (size_t)b * HW4;
    const f4* vb = v4 + (size_t)b * HW4;
    const size_t row = ((size_t)(b * TT + t - 1)) * HW4;
    double s = 0.0;
    for (int j = tid; j < HW4; j += 256) {
        f4 tv = temps[row + j], mv = masks[row + j], bv = bg[j];
        f4 uu = ub[j], vv = vb[j];
        f4 w = tv * mv + bv * (1.f - mv);
        s += (double)hsum(w * (vv * w - 2.f * uu));
    }
    double tot = blk_reduce(s);
    if (tid == 0) err32[b * TP1 + t] = tot;
}

// Fallback (small ws): exact f32 err with on-the-fly w.
__global__ void k_err_f32(const f4* __restrict__ temps, const f4* __restrict__ masks,
                          const f4* __restrict__ bg,
                          const f4* __restrict__ u4, const f4* __restrict__ v4,
                          const int* __restrict__ used, double* __restrict__ err32) {
    const int t = blockIdx.x, b = blockIdx.y, tid = threadIdx.x;
    if (t != 0 && used[b * TP1 + t]) {
        if (tid == 0) err32[b * TP1 + t] = BIGE;
        return;
    }
    const f4* ub = u4 + (size_t)b * HW4;
    const f4* vb = v4 + (size_t)b * HW4;
    double s = 0.0;
    if (t == 0) {
        for (int j = tid; j < HW4; j += 256) {
            f4 uu = ub[j], vv = vb[j];
            s += (double)(25.f * hsum(vv) - 10.f * hsum(uu));
        }
    } else {
        const size_t row = ((size_t)(b * TT + t - 1)) * HW4;
        for (int j = tid; j < HW4; j += 256) {
            f4 tv = temps[row + j], mv = masks[row + j], bv = bg[j];
            f4 uu = ub[j], vv = vb[j];
            f4 w = tv * mv + bv * (1.f - mv);
            s += (double)hsum(w * (vv * w - 2.f * uu));
        }
    }
    double tot = blk_reduce(s);
    if (tid == 0) err32[b * TP1 + t] = tot;
}

// Fused argmin + state update + object emit + (u,v for next step) + bookkeeping.
// LAST step emits recons = A_L + M_L * bg (affine dead-leaves identity).
template <bool FIRST, bool LAST>
__global__ void k_upd(const f4* __restrict__ temps, const f4* __restrict__ masks,
                      const f4* __restrict__ x, const f4* __restrict__ bg,
                      const double* __restrict__ err,
                      int* __restrict__ used, f4* __restrict__ A, f4* __restrict__ M,
                      f4* __restrict__ u, f4* __restrict__ v,
                      f4* __restrict__ out_obj, f4* __restrict__ out_msk,
                      f4* __restrict__ out_rec, float* __restrict__ out_ids, int l) {
    const int tid = threadIdx.x;
    const int gid = blockIdx.x * 256 + tid;      // over B*HW4 (65536), 256 blocks
    const int b = gid >> 12;
    const int p = gid & (HW4 - 1);
    __shared__ int ssel;
    if (tid < 64) {
        double best = 1e301;
        int bi = TP1;
        for (int t = tid; t < TP1; t += 64) {
            double e = err[b * TP1 + t];
            if (e < best) { best = e; bi = t; }   // ascending t per thread: < keeps first
        }
        for (int off = 32; off; off >>= 1) {
            double oe = __shfl_down(best, off);
            int    oi = __shfl_down(bi, off);
            if (oe < best || (oe == best && oi < bi)) { best = oe; bi = oi; }
        }
        if (tid == 0) ssel = bi;
    }
    __syncthreads();
    const int id = ssel;
    f4 st, sm;
    if (id == 0) {
        st = (f4){5.f, 5.f, 5.f, 5.f};
        sm = (f4){1.f, 1.f, 1.f, 1.f};
    } else {
        size_t base = ((size_t)(b * TT + id - 1)) * HW4 + p;
        st = temps[base];
        sm = masks[base];
    }
    f4 a, mp;
    if (FIRST) { a = (f4){0.f, 0.f, 0.f, 0.f}; mp = (f4){1.f, 1.f, 1.f, 1.f}; }
    else       { a = A[gid]; mp = M[gid]; }
    a = a + mp * st * sm;
    mp = mp * (1.f - sm);
    const size_t ob = ((size_t)(b * LL + l)) * HW4 + p;
    out_obj[ob] = st;
    out_msk[ob] = sm;
    if (LAST) {
        out_rec[gid] = a + mp * bg[p];
    } else {
        A[gid] = a; M[gid] = mp;
        f4 xv = x[gid];
        u[gid] = (xv - a) * mp;
        v[gid] = mp * mp;
    }
    if ((blockIdx.x & 15) == 0 && tid == 0) {      // one block per batch
        if (id != 0) used[b * TP1 + id] = 1;
        out_ids[b * LL + l] = (float)id;
    }
}

__global__ void k_uv0(const f4* __restrict__ x, f4* __restrict__ u, f4* __restrict__ v,
                      int* __restrict__ used) {
    int gid = blockIdx.x * blockDim.x + threadIdx.x;
    if (gid < BB * TP1) used[gid] = 0;
    if (gid >= BB * HW4) return;
    u[gid] = x[gid];
    v[gid] = (f4){1.f, 1.f, 1.f, 1.f};
}

static inline void launch_upd(bool first, bool last,
                              const f4* temps, const f4* masks, const f4* x, const f4* bg,
                              const double* err, int* used, f4* A, f4* M,
                              f4* u, f4* v, f4* out_obj, f4* out_msk, f4* out_rec,
                              float* out_ids, int l, hipStream_t stream) {
    if (first)
        k_upd<true, false><<<256, 256, 0, stream>>>(temps, masks, x, bg, err, used, A, M, u, v, out_obj, out_msk, out_rec, out_ids, l);
    else if (last)
        k_upd<false, true><<<256, 256, 0, stream>>>(temps, masks, x, bg, err, used, A, M, u, v, out_obj, out_msk, out_rec, out_ids, l);
    else
        k_upd<false, false><<<256, 256, 0, stream>>>(temps, masks, x, bg, err, used, A, M, u, v, out_obj, out_msk, out_rec, out_ids, l);
}

extern "C" void kernel_launch(void* const* d_in, const int* in_sizes, int n_in,
                              void* d_out, int out_size, void* d_ws, size_t ws_size,
                              hipStream_t stream) {
    const f4* x     = (const f4*)d_in[0];
    const f4* temps = (const f4*)d_in[1];
    const f4* masks = (const f4*)d_in[2];
    const f4* bg    = (const f4*)d_in[3];

    float* out      = (float*)d_out;
    f4*    out_rec  = (f4*)out;                           // B*HW
    f4*    out_obj  = (f4*)(out + 262144);                // B*L*HW
    f4*    out_msk  = (f4*)(out + 262144 + 1572864);      // B*L*HW
    float* out_ids  = out + 262144 + 2 * 1572864;         // B*L

    char* ws = (char*)d_ws;
    f4*     A     = (f4*)(ws + OFF_A);
    f4*     M     = (f4*)(ws + OFF_M);
    f4*     u     = (f4*)(ws + OFF_U);
    f4*     v     = (f4*)(ws + OFF_V);
    double* err32 = (double*)(ws + OFF_ERR32);
    double* err16 = (double*)(ws + OFF_ERR16);
    double* D     = (double*)(ws + OFF_D);
    int*    used  = (int*)(ws + OFF_USED);
    u16x4*  wq    = (u16x4*)(ws + OFF_WQ);

    const bool full = (ws_size >= WS_FULL);

    if (full) {
        k_build<<<dim3(TP1, BB), 256, 0, stream>>>(temps, masks, bg, x, wq, err32, used);
        for (int l = 0; l < LL; ++l) {
            launch_upd(l == 0, l == LL - 1, temps, masks, x, bg, err32, used, A, M, u, v,
                       out_obj, out_msk, out_rec, out_ids, l, stream);
            if (l < LL - 1) {
                k_err16<<<NB_STEP, 256, 0, stream>>>((const u16x8*)wq, u, v, used, err16, D);
                k_refine<<<dim3(TP1, BB), 256, 0, stream>>>(temps, masks, bg, u, v, err16, D, err32);
            }
        }
    } else {
        k_uv0<<<(BB * HW4 + 255) / 256, 256, 0, stream>>>(x, u, v, used);
        for (int l = 0; l < LL; ++l) {
            k_err_f32<<<dim3(TP1, BB), 256, 0, stream>>>(temps, masks, bg, u, v, used, err32);
            launch_upd(l == 0, l == LL - 1, temps, masks, x, bg, err32, used, A, M, u, v,
                       out_obj, out_msk, out_rec, out_ids, l, stream);
        }
    }
}